// Round 5
// baseline (245.151 us; speedup 1.0000x reference)
//
#include <hip/hip_runtime.h>

// (B,N,D,K) = (32, 2048, 512, 256)
#define CB 32
#define CN 2048
#define CD 512
#define CK 256

typedef __bf16 bf16x8 __attribute__((ext_vector_type(8)));
typedef float  f32x4  __attribute__((ext_vector_type(4)));

__device__ __forceinline__ unsigned pk2bf(float a, float b) {   // RNE pack: 2 f32 -> bf16x2
    union { float f; unsigned u; } x, y; x.f = a; y.f = b;
    unsigned ru = x.u + 0x7fffu + ((x.u >> 16) & 1u);
    unsigned rv = y.u + 0x7fffu + ((y.u >> 16) & 1u);
    return (ru >> 16) | (rv & 0xffff0000u);
}

__device__ __forceinline__ unsigned short bf16r(float a) {      // RNE f32 -> bf16
    union { float f; unsigned u; } x; x.f = a;
    unsigned r = x.u + 0x7fffu + ((x.u >> 16) & 1u);
    return (unsigned short)(r >> 16);
}

__device__ __forceinline__ void glds16(const void* g, void* l) {
    __builtin_amdgcn_global_load_lds(
        (const __attribute__((address_space(1))) void*)g,
        (__attribute__((address_space(3))) void*)l, 16, 0, 0);
}

// ---------------- K0: prep = {WiT transpose tiles: blocks 0..31} ∪
//                          {vQp partial GEMV: blocks 32..287} ----------------
__global__ __launch_bounds__(256) void prep_kernel(
        const float* __restrict__ Wi, const float* __restrict__ Wq,
        const float* __restrict__ vQ, const float* __restrict__ bq,
        unsigned short* __restrict__ WiT, float* __restrict__ vQpP)
{
    const int tid = threadIdx.x;
    if (blockIdx.x < 32) {
        // 64x64 tile transpose Wi[d][k] -> WiT[k][d] (bf16), coalesced both sides
        const int t = blockIdx.x;
        const int d0 = (t >> 2) * 64, k0 = (t & 3) * 64;
        __shared__ float sT[64][68];                 // pad 68: 16B-aligned rows
        const int r = tid >> 4, c4 = (tid & 15) * 4;
        #pragma unroll
        for (int i = 0; i < 4; ++i) {
            float4 v = *reinterpret_cast<const float4*>(
                Wi + (size_t)(d0 + r + i * 16) * CK + k0 + c4);
            *reinterpret_cast<float4*>(&sT[r + i * 16][c4]) = v;
        }
        __syncthreads();
        const int k = tid >> 2, dg = (tid & 3) * 16;
        unsigned short __attribute__((aligned(16))) ov[16];
        #pragma unroll
        for (int j = 0; j < 16; ++j) ov[j] = bf16r(sT[dg + j][k]);
        unsigned short* dst = WiT + (size_t)(k0 + k) * CD + d0 + dg;
        *reinterpret_cast<uint4*>(dst)     = *reinterpret_cast<const uint4*>(&ov[0]);
        *reinterpret_cast<uint4*>(dst + 8) = *reinterpret_cast<const uint4*>(&ov[8]);
    } else {
        // vQpP[b][j][k] = sum_{d in 64-slice j} vQ[b][d]*Wq[d][k]  (+bq at j==0)
        const int bb = blockIdx.x - 32;
        const int b = bb >> 3, j = bb & 7;
        __shared__ float sq[64];
        if (tid < 64) sq[tid] = vQ[b * CD + j * 64 + tid];
        __syncthreads();
        float acc = (j == 0) ? bq[tid] : 0.f;
        const float* wq = Wq + (size_t)j * 64 * CK + tid;
        #pragma unroll
        for (int d = 0; d < 64; d += 8) {
            float wv[8];
            #pragma unroll
            for (int u = 0; u < 8; ++u) wv[u] = wq[(d + u) * CK];   // 8 loads in flight
            #pragma unroll
            for (int u = 0; u < 8; ++u) acc += sq[d + u] * wv[u];
        }
        vQpP[(size_t)bb * CK + tid] = acc;
    }
}

// ---------------- K1: fused scores + online-softmax + K-space num ----------------
// OCCUPANCY RESTRUCTURE: BM=64 rows/block, BK=32, 16 K-steps. grid (32, 32).
// 4 waves = 2 row-groups (32 rows) x 2 k-halves (128 cols).
//   acc[2][8] = 64 VGPR  -> ~145 total -> 3 waves/SIMD (launch_bounds 256,3)
//   LDS 2 x 16 KB = 32 KB -> 3 blocks/CU resident -> 12 waves/CU (1.5x prev)
// A private per (row-group), direct global->reg, ping-pong 1 step ahead;
// B staged via swizzled glds double-buffer, 8 conflict-free(2-way) ds_read_b128
// per wave per step. One barrier per K-step.
__global__ __launch_bounds__(256, 3) void scores_fused_kernel(
        const float* __restrict__ vI, const unsigned short* __restrict__ WiT,
        const float* __restrict__ vQpP, const float* __restrict__ Wp,
        float* __restrict__ numP, float* __restrict__ Zp, float* __restrict__ mP)
{
    constexpr int BM = 64, BK = 32;
    __shared__ __align__(16) unsigned short sB[2][CK * BK];   // 2 x 16 KB
    float* fb   = (float*)sB[0];      // aliased AFTER the K-loop only
    float* sred = fb;                 // [2][64] score kh-partials
    float* sS   = fb + 128;           // [64] row scores (later [0..3] Z partials)
    float* sW   = fb + 192;           // [64] exp weights
    float* svq  = fb + 256;           // [256] combined vQp
    float* swp  = fb + 512;           // [256] Wp
    float* snum = fb + 768;           // [2][256] num rg-partials

    const int tid  = threadIdx.x;
    const int b    = blockIdx.y;
    const int n0   = blockIdx.x * BM;
    const int wave = tid >> 6;
    const int lane = tid & 63;
    const int col  = lane & 15;
    const int quad = lane >> 4;
    const int rg   = wave >> 1;       // row-group: rows [32*rg, 32*rg+32)
    const int kh   = wave & 1;        // k-half:   cols [128*kh, 128*kh+128)

    const float* vIb   = vI + ((size_t)b * CN + n0) * CD;
    const float* aBase = vIb + (size_t)(rg * 32 + col) * CD + quad * 8;

    // B glds source offsets (swizzled chunk): instr i covers rows wave*64+i*16..+16
    int gBoff[4];
    #pragma unroll
    for (int i = 0; i < 4; ++i) {
        int row = wave * 64 + i * 16 + (lane >> 2);
        int c   = (lane & 3) ^ ((row >> 1) & 3);
        gBoff[i] = row * CD + c * 8;    // ushort index; +d0 per step
    }

    f32x4 acc[2][8];
    #pragma unroll
    for (int mt = 0; mt < 2; ++mt)
        #pragma unroll
        for (int kt = 0; kt < 8; ++kt)
            acc[mt][kt] = (f32x4){0.f, 0.f, 0.f, 0.f};

    f32x4 aP[4], aQ[4];   // ping-pong A regs: idx = mt*2 + half

    auto loadA = [&](f32x4* dst, int d0) {
        #pragma unroll
        for (int mt = 0; mt < 2; ++mt) {
            const float* p = aBase + (size_t)(mt * 16) * CD + d0;
            dst[mt * 2]     = *reinterpret_cast<const f32x4*>(p);
            dst[mt * 2 + 1] = *reinterpret_cast<const f32x4*>(p + 4);
        }
    };
    auto stageB = [&](int d0, int buf) {
        #pragma unroll
        for (int i = 0; i < 4; ++i)
            glds16(WiT + gBoff[i] + d0,
                   (unsigned short*)sB[buf] + (wave * 4 + i) * 512);
    };
    auto compute = [&](const f32x4* ar, const unsigned short* bufC) {
        bf16x8 af[2];
        #pragma unroll
        for (int mt = 0; mt < 2; ++mt) {
            union { unsigned u[4]; bf16x8 v; } t;
            const f32x4 lo = ar[mt * 2], hi = ar[mt * 2 + 1];
            t.u[0] = pk2bf(lo.x, lo.y); t.u[1] = pk2bf(lo.z, lo.w);
            t.u[2] = pk2bf(hi.x, hi.y); t.u[3] = pk2bf(hi.z, hi.w);
            af[mt] = t.v;
        }
        const int sl = quad ^ ((col >> 1) & 3);   // 2-way aliasing only (free)
        #pragma unroll
        for (int kc = 0; kc < 2; ++kc) {
            bf16x8 bfr[4];
            #pragma unroll
            for (int u = 0; u < 4; ++u) {
                int R = kh * 128 + (kc * 4 + u) * 16 + col;
                bfr[u] = *reinterpret_cast<const bf16x8*>(bufC + R * 32 + sl * 8);
            }
            #pragma unroll
            for (int u = 0; u < 4; ++u)
                #pragma unroll
                for (int mt = 0; mt < 2; ++mt)
                    acc[mt][kc * 4 + u] = __builtin_amdgcn_mfma_f32_16x16x32_bf16(
                        af[mt], bfr[u], acc[mt][kc * 4 + u], 0, 0, 0);
        }
    };

    // prologue: A(0) and B(0) in flight together
    loadA(aP, 0);
    stageB(0, 0);
    __syncthreads();

    for (int tt = 0; tt < 8; ++tt) {
        const int d0 = tt * 64;
        loadA(aQ, d0 + 32);
        stageB(d0 + 32, 1);
        compute(aP, sB[0]);
        __syncthreads();
        if (tt < 7) {
            loadA(aP, d0 + 64);
            stageB(d0 + 64, 0);
        }
        compute(aQ, sB[1]);
        __syncthreads();
    }

    // ---- epilogue 0: combine vQp partials + Wp into LDS (alias on sB[0]) ----
    {
        float a = 0.f;
        #pragma unroll
        for (int j = 0; j < 8; ++j) a += vQpP[(b * 8 + j) * CK + tid];
        svq[tid] = a;
        swp[tid] = Wp[tid];
    }
    __syncthreads();

    // ---- epilogue 1: per-row scores (vIp never materialized) ----
    float vq[8], wp[8];
    #pragma unroll
    for (int kt = 0; kt < 8; ++kt) {
        int k = kh * 128 + kt * 16 + col;
        vq[kt] = svq[k];
        wp[kt] = swp[k];
    }
    float sp[2][4];
    #pragma unroll
    for (int mt = 0; mt < 2; ++mt)
        #pragma unroll
        for (int r = 0; r < 4; ++r) {
            float s = 0.f;
            #pragma unroll
            for (int kt = 0; kt < 8; ++kt) {
                float v = acc[mt][kt][r] + vq[kt];
                v = v > 0.f ? v : 0.01f * v;
                s += v * wp[kt];
            }
            sp[mt][r] = s;
        }
    #pragma unroll
    for (int off = 1; off < 16; off <<= 1)
        #pragma unroll
        for (int mt = 0; mt < 2; ++mt)
            #pragma unroll
            for (int r = 0; r < 4; ++r)
                sp[mt][r] += __shfl_xor(sp[mt][r], off);
    if (col == 0) {
        #pragma unroll
        for (int mt = 0; mt < 2; ++mt)
            #pragma unroll
            for (int r = 0; r < 4; ++r)
                sred[kh * 64 + rg * 32 + mt * 16 + quad * 4 + r] = sp[mt][r];
    }
    __syncthreads();
    if (tid < BM) sS[tid] = sred[tid] + sred[64 + tid];   // add the 2 k-halves
    __syncthreads();

    // ---- epilogue 2: block-local softmax pieces ----
    float m = -1e30f;
    #pragma unroll 8
    for (int i = 0; i < BM; ++i) m = fmaxf(m, sS[i]);
    if (tid < BM) sW[tid] = __expf(sS[tid] - m);
    __syncthreads();
    float z = (tid < BM) ? sW[tid] : 0.f;
    #pragma unroll
    for (int off = 32; off > 0; off >>= 1) z += __shfl_xor(z, off);
    if (lane == 0) sS[wave] = z;     // scores no longer needed; waves 1..3 add 0
    __syncthreads();
    const int pidx = b * 32 + blockIdx.x;
    if (tid == 0) {
        Zp[pidx] = sS[0] + sS[1] + sS[2] + sS[3];
        mP[pidx] = m;
    }

    // ---- epilogue 3: K-space num from acc registers (vI never re-read) ----
    float w8[2][4];
    #pragma unroll
    for (int mt = 0; mt < 2; ++mt)
        #pragma unroll
        for (int r = 0; r < 4; ++r)
            w8[mt][r] = sW[rg * 32 + mt * 16 + quad * 4 + r];
    float nk[8];
    #pragma unroll
    for (int kt = 0; kt < 8; ++kt) {
        float s = 0.f;
        #pragma unroll
        for (int mt = 0; mt < 2; ++mt)
            #pragma unroll
            for (int r = 0; r < 4; ++r)
                s += w8[mt][r] * acc[mt][kt][r];
        s += __shfl_xor(s, 16);      // reduce across quads (rows within frag)
        s += __shfl_xor(s, 32);
        nk[kt] = s;
    }
    if (quad == 0) {
        #pragma unroll
        for (int kt = 0; kt < 8; ++kt)
            snum[rg * 256 + kh * 128 + kt * 16 + col] = nk[kt];
    }
    __syncthreads();
    numP[(size_t)pidx * CK + tid] = snum[tid] + snum[256 + tid];  // sum row-groups
}

// ---------------- K2: combine partials -> out = num/Z + vQp (elementwise) ----------------
__global__ __launch_bounds__(256) void finalize_kernel(
        const float* __restrict__ numP, const float* __restrict__ Zp,
        const float* __restrict__ mP, const float* __restrict__ vQpP,
        float* __restrict__ out)
{
    const int b = blockIdx.x, tid = threadIdx.x;
    float M = -1e30f;
    #pragma unroll
    for (int j = 0; j < 32; ++j) M = fmaxf(M, mP[b * 32 + j]);
    float w[32]; float Zt = 0.f;
    #pragma unroll
    for (int j = 0; j < 32; ++j) {
        w[j] = __expf(mP[b * 32 + j] - M);
        Zt += w[j] * Zp[b * 32 + j];
    }
    const float inv = 1.f / Zt;
    float s = 0.f;
    #pragma unroll
    for (int j = 0; j < 32; ++j) s += w[j] * numP[(size_t)(b * 32 + j) * CK + tid];
    float vq = 0.f;
    #pragma unroll
    for (int j = 0; j < 8; ++j) vq += vQpP[(size_t)(b * 8 + j) * CK + tid];
    out[b * CK + tid] = s * inv + vq;
}

extern "C" void kernel_launch(void* const* d_in, const int* in_sizes, int n_in,
                              void* d_out, int out_size, void* d_ws, size_t ws_size,
                              hipStream_t stream)
{
    const float* vI = (const float*)d_in[0];   // [B,N,D]
    const float* vQ = (const float*)d_in[1];   // [B,D]
    const float* Wi = (const float*)d_in[2];   // [D,K]
    const float* Wq = (const float*)d_in[3];   // [D,K]
    const float* bq = (const float*)d_in[4];   // [K]
    const float* Wp = (const float*)d_in[5];   // [K,1]
    // d_in[6] = bp: softmax-invariant, unused
    float* out = (float*)d_out;                // [B,K]

    char* ws = (char*)d_ws;
    float*          vQpP = (float*)(ws);                    // 256 KB  [32*8][256]
    unsigned short* WiT  = (unsigned short*)(ws + 262144);  // 256 KB  [256][512]
    float*          numP = (float*)(ws + 524288);           //   1 MB  [32*32][256]
    float*          Zp   = (float*)(ws + 524288 + 1048576); //   4 KB
    float*          mP   = (float*)(ws + 524288 + 1048576 + 4096); // 4 KB

    prep_kernel        <<<288, 256, 0, stream>>>(Wi, Wq, vQ, bq, WiT, vQpP);
    scores_fused_kernel<<<dim3(CN / 64, CB), 256, 0, stream>>>(vI, WiT, vQpP, Wp,
                                                               numP, Zp, mP);
    finalize_kernel    <<<CB, 256, 0, stream>>>(numP, Zp, mP, vQpP, out);
}

// Round 6
// 229.075 us; speedup vs baseline: 1.0702x; 1.0702x over previous
//
#include <hip/hip_runtime.h>

// (B,N,D,K) = (32, 2048, 512, 256)
#define CB 32
#define CN 2048
#define CD 512
#define CK 256

typedef __bf16 bf16x8 __attribute__((ext_vector_type(8)));
typedef float  f32x4  __attribute__((ext_vector_type(4)));

__device__ __forceinline__ unsigned pk2bf(float a, float b) {   // RNE pack: 2 f32 -> bf16x2
    union { float f; unsigned u; } x, y; x.f = a; y.f = b;
    unsigned ru = x.u + 0x7fffu + ((x.u >> 16) & 1u);
    unsigned rv = y.u + 0x7fffu + ((y.u >> 16) & 1u);
    return (ru >> 16) | (rv & 0xffff0000u);
}

__device__ __forceinline__ unsigned short bf16r(float a) {      // RNE f32 -> bf16
    union { float f; unsigned u; } x; x.f = a;
    unsigned r = x.u + 0x7fffu + ((x.u >> 16) & 1u);
    return (unsigned short)(r >> 16);
}

__device__ __forceinline__ void glds16(const void* g, void* l) {
    __builtin_amdgcn_global_load_lds(
        (const __attribute__((address_space(1))) void*)g,
        (__attribute__((address_space(3))) void*)l, 16, 0, 0);
}

// ---------------- K0: prep = {WiT transpose tiles: blocks 0..31} ∪
//                          {vQp partial GEMV: blocks 32..287} ----------------
__global__ __launch_bounds__(256) void prep_kernel(
        const float* __restrict__ Wi, const float* __restrict__ Wq,
        const float* __restrict__ vQ, const float* __restrict__ bq,
        unsigned short* __restrict__ WiT, float* __restrict__ vQpP)
{
    const int tid = threadIdx.x;
    if (blockIdx.x < 32) {
        // 64x64 tile transpose Wi[d][k] -> WiT[k][d] (bf16), coalesced both sides
        const int t = blockIdx.x;
        const int d0 = (t >> 2) * 64, k0 = (t & 3) * 64;
        __shared__ float sT[64][68];                 // pad 68: 16B-aligned rows
        const int r = tid >> 4, c4 = (tid & 15) * 4;
        #pragma unroll
        for (int i = 0; i < 4; ++i) {
            float4 v = *reinterpret_cast<const float4*>(
                Wi + (size_t)(d0 + r + i * 16) * CK + k0 + c4);
            *reinterpret_cast<float4*>(&sT[r + i * 16][c4]) = v;
        }
        __syncthreads();
        const int k = tid >> 2, dg = (tid & 3) * 16;
        unsigned short __attribute__((aligned(16))) ov[16];
        #pragma unroll
        for (int j = 0; j < 16; ++j) ov[j] = bf16r(sT[dg + j][k]);
        unsigned short* dst = WiT + (size_t)(k0 + k) * CD + d0 + dg;
        *reinterpret_cast<uint4*>(dst)     = *reinterpret_cast<const uint4*>(&ov[0]);
        *reinterpret_cast<uint4*>(dst + 8) = *reinterpret_cast<const uint4*>(&ov[8]);
    } else {
        // vQpP[b][j][k] = sum_{d in 64-slice j} vQ[b][d]*Wq[d][k]  (+bq at j==0)
        const int bb = blockIdx.x - 32;
        const int b = bb >> 3, j = bb & 7;
        __shared__ float sq[64];
        if (tid < 64) sq[tid] = vQ[b * CD + j * 64 + tid];
        __syncthreads();
        float acc = (j == 0) ? bq[tid] : 0.f;
        const float* wq = Wq + (size_t)j * 64 * CK + tid;
        #pragma unroll
        for (int d = 0; d < 64; d += 8) {
            float wv[8];
            #pragma unroll
            for (int u = 0; u < 8; ++u) wv[u] = wq[(d + u) * CK];   // 8 loads in flight
            #pragma unroll
            for (int u = 0; u < 8; ++u) acc += sq[d + u] * wv[u];
        }
        vQpP[(size_t)bb * CK + tid] = acc;
    }
}

// ---------------- K1: fused scores + online-softmax + K-space num ----------------
// Round-4 structure (best measured: ~58us) + T4 counted-vmcnt barriers.
// BM=128 rows/block, BK=64, 8 K-steps. grid (16, 32).
// Wave w owns A-rows [32w,32w+32) x ALL 256 K-cols; A direct global->reg,
// ping-pong 1 step ahead; B via swizzled glds double-buffer.
// Per step, issue order pinned by sched_barrier(0):
//   [glds B(t+1) x8]  |  [A(t+1) x8]  | compute(t) | vmcnt(8) ; s_barrier
// vmcnt(8) drains exactly the 8 OLDEST outstanding (the glds, FIFO per m135),
// so B(t+1) is LDS-visible at the barrier while A(t+1) stays in flight and is
// waited only at its first use (compiler-inserted) early in step t+1.
__global__ __launch_bounds__(256, 2) void scores_fused_kernel(
        const float* __restrict__ vI, const unsigned short* __restrict__ WiT,
        const float* __restrict__ vQpP, const float* __restrict__ Wp,
        float* __restrict__ numP, float* __restrict__ Zp, float* __restrict__ mP)
{
    constexpr int BM = 128, BK = 64;
    __shared__ __align__(16) unsigned short sB[2][CK * BK];   // 2 x 32 KB
    float* fb   = (float*)sB[0];      // aliased AFTER the K-loop only
    float* svq  = fb;                 // [256] combined vQp
    float* swp  = fb + 256;           // [256] Wp
    float* sS   = fb + 512;           // [128] row scores
    float* sW   = fb + 640;           // [128] exp weights
    float* snum = fb + 768;           // [4][256] num wave-partials

    const int tid  = threadIdx.x;
    const int b    = blockIdx.y;
    const int n0   = blockIdx.x * BM;
    const int wave = tid >> 6;
    const int lane = tid & 63;
    const int col  = lane & 15;
    const int quad = lane >> 4;

    const float* vIb   = vI + ((size_t)b * CN + n0) * CD;
    // A-row for (mt): 32*wave + mt*16 + col ; k-chunk quad*8 (+s*32)
    const float* aBase = vIb + (size_t)(wave * 32 + col) * CD + quad * 8;

    // B glds source offsets (swizzled chunk): instr i covers rows wave*64+i*8 .. +8
    int gBoff[8];
    #pragma unroll
    for (int i = 0; i < 8; ++i) {
        int row = wave * 64 + i * 8 + (lane >> 3);
        int c   = (lane & 7) ^ (row & 7);
        gBoff[i] = row * CD + c * 8;    // ushort index; +d0 per chunk
    }

    f32x4 acc[2][16];
    #pragma unroll
    for (int mt = 0; mt < 2; ++mt)
        #pragma unroll
        for (int kt = 0; kt < 16; ++kt)
            acc[mt][kt] = (f32x4){0.f, 0.f, 0.f, 0.f};

    f32x4 aP[8], aQ[8];   // ping-pong A regs: idx = mt*4 + s*2 + half

    auto loadA = [&](f32x4* dst, int d0) {
        #pragma unroll
        for (int mt = 0; mt < 2; ++mt)
            #pragma unroll
            for (int s = 0; s < 2; ++s) {
                const float* p = aBase + (size_t)(mt * 16) * CD + d0 + s * 32;
                dst[mt * 4 + s * 2]     = *reinterpret_cast<const f32x4*>(p);
                dst[mt * 4 + s * 2 + 1] = *reinterpret_cast<const f32x4*>(p + 4);
            }
    };
    auto stageB = [&](int d0, int buf) {
        #pragma unroll
        for (int i = 0; i < 8; ++i)
            glds16(WiT + gBoff[i] + d0,
                   (unsigned short*)sB[buf] + (wave * 8 + i) * 512);
    };
    auto compute = [&](const f32x4* ar, const unsigned short* bufC) {
        bf16x8 af[2][2];
        #pragma unroll
        for (int mt = 0; mt < 2; ++mt)
            #pragma unroll
            for (int s = 0; s < 2; ++s) {
                union { unsigned u[4]; bf16x8 v; } t;
                const f32x4 lo = ar[mt * 4 + s * 2], hi = ar[mt * 4 + s * 2 + 1];
                t.u[0] = pk2bf(lo.x, lo.y); t.u[1] = pk2bf(lo.z, lo.w);
                t.u[2] = pk2bf(hi.x, hi.y); t.u[3] = pk2bf(hi.z, hi.w);
                af[mt][s] = t.v;
            }
        __builtin_amdgcn_s_setprio(1);
        #pragma unroll
        for (int s = 0; s < 2; ++s) {
            const int slot = (4 * s + quad) ^ (col & 7);
            #pragma unroll
            for (int kc = 0; kc < 4; ++kc) {
                bf16x8 bfr[4];
                #pragma unroll
                for (int u = 0; u < 4; ++u) {
                    int R = (kc * 4 + u) * 16 + col;
                    bfr[u] = *reinterpret_cast<const bf16x8*>(bufC + R * 64 + slot * 8);
                }
                #pragma unroll
                for (int u = 0; u < 4; ++u)
                    #pragma unroll
                    for (int mt = 0; mt < 2; ++mt)
                        acc[mt][kc * 4 + u] = __builtin_amdgcn_mfma_f32_16x16x32_bf16(
                            af[mt][s], bfr[u], acc[mt][kc * 4 + u], 0, 0, 0);
            }
        }
        __builtin_amdgcn_s_setprio(0);
    };

    // prologue: A(0) and B(0) in flight together; full drain once
    loadA(aP, 0);
    stageB(0, 0);
    __syncthreads();

    for (int t = 0; t < 8; ++t) {
        const int d0 = t * BK;
        if (t < 7) {
            stageB(d0 + BK, (t + 1) & 1);        // oldest 8 in vmcnt FIFO
            __builtin_amdgcn_sched_barrier(0);   // pin glds-before-A order
            loadA((t & 1) ? aP : aQ, d0 + BK);   // newest 8: may fly past barrier
            __builtin_amdgcn_sched_barrier(0);
        }
        compute((t & 1) ? aQ : aP, sB[t & 1]);
        if (t < 7) {
            asm volatile("s_waitcnt vmcnt(8)" ::: "memory");  // drain glds only
        } else {
            asm volatile("s_waitcnt vmcnt(0)" ::: "memory");
        }
        __builtin_amdgcn_s_barrier();
    }
    __syncthreads();   // once: full fence before LDS aliasing

    // ---- epilogue 0: combine vQp partials + Wp into LDS (alias on sB[0]) ----
    {
        float a = 0.f;
        #pragma unroll
        for (int j = 0; j < 8; ++j) a += vQpP[(b * 8 + j) * CK + tid];
        svq[tid] = a;
        swp[tid] = Wp[tid];
    }
    __syncthreads();

    // ---- epilogue 1: per-row scores ----
    float vq[16], wp[16];
    #pragma unroll
    for (int kt = 0; kt < 16; ++kt) {
        vq[kt] = svq[kt * 16 + col];
        wp[kt] = swp[kt * 16 + col];
    }
    float sp[2][4];
    #pragma unroll
    for (int mt = 0; mt < 2; ++mt)
        #pragma unroll
        for (int r = 0; r < 4; ++r) {
            float s = 0.f;
            #pragma unroll
            for (int kt = 0; kt < 16; ++kt) {
                float v = acc[mt][kt][r] + vq[kt];
                v = v > 0.f ? v : 0.01f * v;
                s += v * wp[kt];
            }
            sp[mt][r] = s;
        }
    #pragma unroll
    for (int off = 1; off < 16; off <<= 1)
        #pragma unroll
        for (int mt = 0; mt < 2; ++mt)
            #pragma unroll
            for (int r = 0; r < 4; ++r)
                sp[mt][r] += __shfl_xor(sp[mt][r], off);
    if (col == 0) {
        #pragma unroll
        for (int mt = 0; mt < 2; ++mt)
            #pragma unroll
            for (int r = 0; r < 4; ++r)
                sS[wave * 32 + mt * 16 + quad * 4 + r] = sp[mt][r];
    }
    __syncthreads();

    // ---- epilogue 2: block-local softmax pieces ----
    float m = -1e30f;
    #pragma unroll 8
    for (int i = 0; i < BM; ++i) m = fmaxf(m, sS[i]);
    if (tid < BM) sW[tid] = __expf(sS[tid] - m);
    __syncthreads();
    float z = (tid < BM) ? sW[tid] : 0.f;
    #pragma unroll
    for (int off = 32; off > 0; off >>= 1) z += __shfl_xor(z, off);
    if (lane == 0) sS[wave] = z;     // scores no longer needed
    __syncthreads();
    const int pidx = b * 16 + blockIdx.x;
    if (tid == 0) {
        Zp[pidx] = sS[0] + sS[1] + sS[2] + sS[3];
        mP[pidx] = m;
    }

    // ---- epilogue 3: K-space num from acc registers (vI never re-read) ----
    float w8[2][4];
    #pragma unroll
    for (int mt = 0; mt < 2; ++mt)
        #pragma unroll
        for (int r = 0; r < 4; ++r)
            w8[mt][r] = sW[wave * 32 + mt * 16 + quad * 4 + r];
    float nk[16];
    #pragma unroll
    for (int kt = 0; kt < 16; ++kt) {
        float s = 0.f;
        #pragma unroll
        for (int mt = 0; mt < 2; ++mt)
            #pragma unroll
            for (int r = 0; r < 4; ++r)
                s += w8[mt][r] * acc[mt][kt][r];
        s += __shfl_xor(s, 16);      // reduce across quads (rows)
        s += __shfl_xor(s, 32);
        nk[kt] = s;
    }
    if (quad == 0) {
        #pragma unroll
        for (int kt = 0; kt < 16; ++kt)
            snum[wave * 256 + kt * 16 + col] = nk[kt];
    }
    __syncthreads();
    numP[(size_t)pidx * CK + tid] =
        snum[tid] + snum[256 + tid] + snum[512 + tid] + snum[768 + tid];
}

// ---------------- K2: combine partials -> out = num/Z + vQp (elementwise) ----------------
__global__ __launch_bounds__(256) void finalize_kernel(
        const float* __restrict__ numP, const float* __restrict__ Zp,
        const float* __restrict__ mP, const float* __restrict__ vQpP,
        float* __restrict__ out)
{
    const int b = blockIdx.x, tid = threadIdx.x;
    float M = -1e30f;
    #pragma unroll
    for (int j = 0; j < 16; ++j) M = fmaxf(M, mP[b * 16 + j]);
    float w[16]; float Zt = 0.f;
    #pragma unroll
    for (int j = 0; j < 16; ++j) {
        w[j] = __expf(mP[b * 16 + j] - M);
        Zt += w[j] * Zp[b * 16 + j];
    }
    const float inv = 1.f / Zt;
    float s = 0.f;
    #pragma unroll
    for (int j = 0; j < 16; ++j) s += w[j] * numP[(size_t)(b * 16 + j) * CK + tid];
    float vq = 0.f;
    #pragma unroll
    for (int j = 0; j < 8; ++j) vq += vQpP[(size_t)(b * 8 + j) * CK + tid];
    out[b * CK + tid] = s * inv + vq;
}

extern "C" void kernel_launch(void* const* d_in, const int* in_sizes, int n_in,
                              void* d_out, int out_size, void* d_ws, size_t ws_size,
                              hipStream_t stream)
{
    const float* vI = (const float*)d_in[0];   // [B,N,D]
    const float* vQ = (const float*)d_in[1];   // [B,D]
    const float* Wi = (const float*)d_in[2];   // [D,K]
    const float* Wq = (const float*)d_in[3];   // [D,K]
    const float* bq = (const float*)d_in[4];   // [K]
    const float* Wp = (const float*)d_in[5];   // [K,1]
    // d_in[6] = bp: softmax-invariant, unused
    float* out = (float*)d_out;                // [B,K]

    char* ws = (char*)d_ws;
    float*          vQpP = (float*)(ws);                   // 256 KB  [32*8][256]
    unsigned short* WiT  = (unsigned short*)(ws + 262144); // 256 KB  [256][512]
    float*          numP = (float*)(ws + 524288);          // 512 KB  [32*16][256]
    float*          Zp   = (float*)(ws + 524288 + 524288); //   2 KB
    float*          mP   = (float*)(ws + 1048576 + 2048);  //   2 KB

    prep_kernel        <<<288, 256, 0, stream>>>(Wi, Wq, vQ, bq, WiT, vQpP);
    scores_fused_kernel<<<dim3(CN / 128, CB), 256, 0, stream>>>(vI, WiT, vQpP, Wp,
                                                                numP, Zp, mP);
    finalize_kernel    <<<CB, 256, 0, stream>>>(numP, Zp, mP, vQpP, out);
}

// Round 7
// 225.637 us; speedup vs baseline: 1.0865x; 1.0152x over previous
//
#include <hip/hip_runtime.h>

// (B,N,D,K) = (32, 2048, 512, 256)
#define CB 32
#define CN 2048
#define CD 512
#define CK 256

typedef __bf16 bf16x8 __attribute__((ext_vector_type(8)));
typedef float  f32x4  __attribute__((ext_vector_type(4)));

__device__ __forceinline__ unsigned pk2bf(float a, float b) {   // RNE pack: 2 f32 -> bf16x2
    union { float f; unsigned u; } x, y; x.f = a; y.f = b;
    unsigned ru = x.u + 0x7fffu + ((x.u >> 16) & 1u);
    unsigned rv = y.u + 0x7fffu + ((y.u >> 16) & 1u);
    return (ru >> 16) | (rv & 0xffff0000u);
}

__device__ __forceinline__ unsigned short bf16r(float a) {      // RNE f32 -> bf16
    union { float f; unsigned u; } x; x.f = a;
    unsigned r = x.u + 0x7fffu + ((x.u >> 16) & 1u);
    return (unsigned short)(r >> 16);
}

__device__ __forceinline__ void glds16(const void* g, void* l) {
    __builtin_amdgcn_global_load_lds(
        (const __attribute__((address_space(1))) void*)g,
        (__attribute__((address_space(3))) void*)l, 16, 0, 0);
}

// ---------------- K0: prep = {WiT transpose tiles: blocks 0..31} ∪
//                          {vQp partial GEMV: blocks 32..287} ----------------
__global__ __launch_bounds__(256) void prep_kernel(
        const float* __restrict__ Wi, const float* __restrict__ Wq,
        const float* __restrict__ vQ, const float* __restrict__ bq,
        unsigned short* __restrict__ WiT, float* __restrict__ vQpP)
{
    const int tid = threadIdx.x;
    if (blockIdx.x < 32) {
        // 64x64 tile transpose Wi[d][k] -> WiT[k][d] (bf16), coalesced both sides
        const int t = blockIdx.x;
        const int d0 = (t >> 2) * 64, k0 = (t & 3) * 64;
        __shared__ float sT[64][68];                 // pad 68: 16B-aligned rows
        const int r = tid >> 4, c4 = (tid & 15) * 4;
        #pragma unroll
        for (int i = 0; i < 4; ++i) {
            float4 v = *reinterpret_cast<const float4*>(
                Wi + (size_t)(d0 + r + i * 16) * CK + k0 + c4);
            *reinterpret_cast<float4*>(&sT[r + i * 16][c4]) = v;
        }
        __syncthreads();
        const int k = tid >> 2, dg = (tid & 3) * 16;
        unsigned short __attribute__((aligned(16))) ov[16];
        #pragma unroll
        for (int j = 0; j < 16; ++j) ov[j] = bf16r(sT[dg + j][k]);
        unsigned short* dst = WiT + (size_t)(k0 + k) * CD + d0 + dg;
        *reinterpret_cast<uint4*>(dst)     = *reinterpret_cast<const uint4*>(&ov[0]);
        *reinterpret_cast<uint4*>(dst + 8) = *reinterpret_cast<const uint4*>(&ov[8]);
    } else {
        // vQpP[b][j][k] = sum_{d in 64-slice j} vQ[b][d]*Wq[d][k]  (+bq at j==0)
        const int bb = blockIdx.x - 32;
        const int b = bb >> 3, j = bb & 7;
        __shared__ float sq[64];
        if (tid < 64) sq[tid] = vQ[b * CD + j * 64 + tid];
        __syncthreads();
        float acc = (j == 0) ? bq[tid] : 0.f;
        const float* wq = Wq + (size_t)j * 64 * CK + tid;
        #pragma unroll
        for (int d = 0; d < 64; d += 8) {
            float wv[8];
            #pragma unroll
            for (int u = 0; u < 8; ++u) wv[u] = wq[(d + u) * CK];   // 8 loads in flight
            #pragma unroll
            for (int u = 0; u < 8; ++u) acc += sq[d + u] * wv[u];
        }
        vQpP[(size_t)bb * CK + tid] = acc;
    }
}

// ---------------- K1: fused scores + softmax pieces + K-space num ----------------
// BARRIER-FREE INNER LOOP (d-split phase-resident B):
//   BM=256 rows/block, 512 threads (8 waves x 32 rows), grid (8,32) = 256 blocks
//   = exactly 1 block/CU (128 KB LDS), no tail, no XCD concerns.
//   Phase p in {0,1}: B-chunk = WiT[256 k][d in 256p..256p+256) resident in LDS
//   (128 KB, XOR-swizzled; staged via inverse-swizzled glds sources).
//   Within a phase: 4 d-steps of 64, ZERO barriers — each wave streams its A rows
//   global->reg (ping-pong, 1 step ahead) against static LDS B. acc accumulates
//   across phases (contraction dim), so vI is read EXACTLY once.
//   Sync events per block: prologue stage, mid restage, epilogue. That's it.
__global__ __launch_bounds__(512, 2) void scores_fused_kernel(
        const float* __restrict__ vI, const unsigned short* __restrict__ WiT,
        const float* __restrict__ vQpP, const float* __restrict__ Wp,
        float* __restrict__ numP, float* __restrict__ Zp, float* __restrict__ mP)
{
    constexpr int BM = 256;
    __shared__ __align__(16) unsigned short sBh[CK * 256];   // [256 k][256 d] bf16 = 128 KB
    float* fb   = (float*)sBh;        // aliased AFTER the K-loop only
    float* svq  = fb;                 // [256] combined vQp
    float* swp  = fb + 256;           // [256] Wp
    float* sS   = fb + 512;           // [256] row scores
    float* sW   = fb + 768;           // [256] exp weights
    float* sZ   = fb + 1024;          // [8]
    float* snum = fb + 1040;          // [8][256] num wave-partials

    const int tid  = threadIdx.x;
    const int b    = blockIdx.y;
    const int n0   = blockIdx.x * BM;
    const int wave = tid >> 6;        // 0..7
    const int lane = tid & 63;
    const int col  = lane & 15;
    const int quad = lane >> 4;

    const float* vIb   = vI + ((size_t)b * CN + n0) * CD;
    // wave owns rows [32*wave, 32*wave+32); lane(col,quad) holds row 32w+mt*16+col,
    // d-chunk quad*8 (+s*32) within each 64-wide step
    const float* aBase = vIb + (size_t)(wave * 32 + col) * CD + quad * 8;

    f32x4 acc[2][16];
    #pragma unroll
    for (int mt = 0; mt < 2; ++mt)
        #pragma unroll
        for (int kt = 0; kt < 16; ++kt)
            acc[mt][kt] = (f32x4){0.f, 0.f, 0.f, 0.f};

    f32x4 aP[8], aQ[8];   // ping-pong A regs: idx = mt*4 + s*2 + half

    auto loadA = [&](f32x4* dst, int d0) {    // d0 = global d (0..511)
        #pragma unroll
        for (int mt = 0; mt < 2; ++mt)
            #pragma unroll
            for (int s = 0; s < 2; ++s) {
                const float* p = aBase + (size_t)(mt * 16) * CD + d0 + s * 32;
                dst[mt * 4 + s * 2]     = *reinterpret_cast<const f32x4*>(p);
                dst[mt * 4 + s * 2 + 1] = *reinterpret_cast<const f32x4*>(p + 4);
            }
    };

    // Stage phase-p B-chunk: LDS row k (512 B) holds WiT[k][256p + dl] with byte
    // swizzle dlb -> dlb ^ ((k&7)<<4). glds writes linearly (base + lane*16), so
    // the SOURCE carries the inverse swizzle (both-sides rule). 2 k-rows per instr;
    // wave w stages k in [32w, 32w+32) -> 16 glds/wave, 128 KB total.
    auto stageB = [&](int p) {
        #pragma unroll
        for (int i = 0; i < 16; ++i) {
            const int k0  = wave * 32 + i * 2;
            const int k   = k0 + (lane >> 5);
            const int dlb = ((lane & 31) * 16) ^ ((k & 7) << 4);
            glds16(WiT + (size_t)k * CD + p * 256 + (dlb >> 1),
                   (unsigned short*)sBh + k0 * 256);
        }
    };

    // compute one d-step (phase-local tl in 0..3) against resident B
    auto compute = [&](int tl, const f32x4* ar) {
        bf16x8 af[2][2];
        #pragma unroll
        for (int mt = 0; mt < 2; ++mt)
            #pragma unroll
            for (int s = 0; s < 2; ++s) {
                union { unsigned u[4]; bf16x8 v; } t;
                const f32x4 lo = ar[mt * 4 + s * 2], hi = ar[mt * 4 + s * 2 + 1];
                t.u[0] = pk2bf(lo.x, lo.y); t.u[1] = pk2bf(lo.z, lo.w);
                t.u[2] = pk2bf(hi.x, hi.y); t.u[3] = pk2bf(hi.z, hi.w);
                af[mt][s] = t.v;
            }
        #pragma unroll
        for (int s = 0; s < 2; ++s) {
            // frag(kt): LDS bytes (kt*16+col)*512 + tl*128 + (((s*4+quad)^(col&7))<<4)
            const int slot = ((s * 4 + quad) ^ (col & 7)) << 4;
            const unsigned short* base = sBh + col * 256 + ((tl * 128 + slot) >> 1);
            #pragma unroll
            for (int kc = 0; kc < 4; ++kc) {
                bf16x8 bfr[4];
                #pragma unroll
                for (int u = 0; u < 4; ++u)
                    bfr[u] = *reinterpret_cast<const bf16x8*>(
                        base + (size_t)(kc * 4 + u) * 16 * 256);
                #pragma unroll
                for (int u = 0; u < 4; ++u)
                    #pragma unroll
                    for (int mt = 0; mt < 2; ++mt)
                        acc[mt][kc * 4 + u] = __builtin_amdgcn_mfma_f32_16x16x32_bf16(
                            af[mt][s], bfr[u], acc[mt][kc * 4 + u], 0, 0, 0);
            }
        }
    };

    // prologue: A(0) + B-phase0 in flight
    loadA(aP, 0);
    stageB(0);
    __syncthreads();

    // ---- phase 0: d in [0,256), 4 steps, NO barriers ----
    #pragma unroll
    for (int t = 0; t < 4; ++t) {
        loadA((t & 1) ? aP : aQ, (t + 1) * 64);   // t=3 prefetches phase-1's first chunk
        compute(t, (t & 1) ? aQ : aP);
    }

    // ---- mid: restage B for phase 1 (B0 reads all done after barrier) ----
    __syncthreads();
    stageB(1);
    asm volatile("s_waitcnt vmcnt(0)" ::: "memory");
    __builtin_amdgcn_s_barrier();

    // ---- phase 1: d in [256,512), 4 steps, NO barriers ----
    #pragma unroll
    for (int t = 4; t < 8; ++t) {
        if (t < 7) loadA((t & 1) ? aP : aQ, (t + 1) * 64);
        compute(t & 3, (t & 1) ? aQ : aP);
    }
    __syncthreads();   // all B reads done; safe to alias LDS

    // ---- epilogue 0: combine vQp partials + Wp into LDS ----
    if (tid < CK) {
        float a = 0.f;
        #pragma unroll
        for (int j = 0; j < 8; ++j) a += vQpP[(b * 8 + j) * CK + tid];
        svq[tid] = a;
        swp[tid] = Wp[tid];
    }
    __syncthreads();

    // ---- epilogue 1: per-row scores (each wave owns ALL k for its rows) ----
    float vq[16], wp[16];
    #pragma unroll
    for (int kt = 0; kt < 16; ++kt) {
        vq[kt] = svq[kt * 16 + col];
        wp[kt] = swp[kt * 16 + col];
    }
    float sp[2][4];
    #pragma unroll
    for (int mt = 0; mt < 2; ++mt)
        #pragma unroll
        for (int r = 0; r < 4; ++r) {
            float s = 0.f;
            #pragma unroll
            for (int kt = 0; kt < 16; ++kt) {
                float v = acc[mt][kt][r] + vq[kt];
                v = v > 0.f ? v : 0.01f * v;
                s += v * wp[kt];
            }
            sp[mt][r] = s;
        }
    #pragma unroll
    for (int off = 1; off < 16; off <<= 1)
        #pragma unroll
        for (int mt = 0; mt < 2; ++mt)
            #pragma unroll
            for (int r = 0; r < 4; ++r)
                sp[mt][r] += __shfl_xor(sp[mt][r], off);
    if (col == 0) {
        #pragma unroll
        for (int mt = 0; mt < 2; ++mt)
            #pragma unroll
            for (int r = 0; r < 4; ++r)
                sS[wave * 32 + mt * 16 + quad * 4 + r] = sp[mt][r];
    }
    __syncthreads();

    // ---- epilogue 2: block-local softmax pieces (256 rows) ----
    float m = -1e30f;
    #pragma unroll 8
    for (int i = 0; i < BM; ++i) m = fmaxf(m, sS[i]);
    if (tid < BM) sW[tid] = __expf(sS[tid] - m);
    __syncthreads();
    float z = (tid < BM) ? sW[tid] : 0.f;
    #pragma unroll
    for (int off = 32; off > 0; off >>= 1) z += __shfl_xor(z, off);
    if (lane == 0 && wave < 4) sZ[wave] = z;
    __syncthreads();
    const int pidx = b * 8 + blockIdx.x;
    if (tid == 0) {
        Zp[pidx] = sZ[0] + sZ[1] + sZ[2] + sZ[3];
        mP[pidx] = m;
    }

    // ---- epilogue 3: K-space num from acc registers (vI never re-read) ----
    float w8[2][4];
    #pragma unroll
    for (int mt = 0; mt < 2; ++mt)
        #pragma unroll
        for (int r = 0; r < 4; ++r)
            w8[mt][r] = sW[wave * 32 + mt * 16 + quad * 4 + r];
    float nk[16];
    #pragma unroll
    for (int kt = 0; kt < 16; ++kt) {
        float s = 0.f;
        #pragma unroll
        for (int mt = 0; mt < 2; ++mt)
            #pragma unroll
            for (int r = 0; r < 4; ++r)
                s += w8[mt][r] * acc[mt][kt][r];
        s += __shfl_xor(s, 16);      // reduce across quads (rows)
        s += __shfl_xor(s, 32);
        nk[kt] = s;
    }
    if (quad == 0) {
        #pragma unroll
        for (int kt = 0; kt < 16; ++kt)
            snum[wave * 256 + kt * 16 + col] = nk[kt];
    }
    __syncthreads();
    if (tid < CK) {
        float s = 0.f;
        #pragma unroll
        for (int w = 0; w < 8; ++w) s += snum[w * 256 + tid];
        numP[(size_t)pidx * CK + tid] = s;
    }
}

// ---------------- K2: combine partials -> out = num/Z + vQp (elementwise) ----------------
__global__ __launch_bounds__(256) void finalize_kernel(
        const float* __restrict__ numP, const float* __restrict__ Zp,
        const float* __restrict__ mP, const float* __restrict__ vQpP,
        float* __restrict__ out)
{
    const int b = blockIdx.x, tid = threadIdx.x;
    float M = -1e30f;
    #pragma unroll
    for (int j = 0; j < 8; ++j) M = fmaxf(M, mP[b * 8 + j]);
    float w[8]; float Zt = 0.f;
    #pragma unroll
    for (int j = 0; j < 8; ++j) {
        w[j] = __expf(mP[b * 8 + j] - M);
        Zt += w[j] * Zp[b * 8 + j];
    }
    const float inv = 1.f / Zt;
    float s = 0.f;
    #pragma unroll
    for (int j = 0; j < 8; ++j) s += w[j] * numP[(size_t)(b * 8 + j) * CK + tid];
    float vq = 0.f;
    #pragma unroll
    for (int j = 0; j < 8; ++j) vq += vQpP[(size_t)(b * 8 + j) * CK + tid];
    out[b * CK + tid] = s * inv + vq;
}

extern "C" void kernel_launch(void* const* d_in, const int* in_sizes, int n_in,
                              void* d_out, int out_size, void* d_ws, size_t ws_size,
                              hipStream_t stream)
{
    const float* vI = (const float*)d_in[0];   // [B,N,D]
    const float* vQ = (const float*)d_in[1];   // [B,D]
    const float* Wi = (const float*)d_in[2];   // [D,K]
    const float* Wq = (const float*)d_in[3];   // [D,K]
    const float* bq = (const float*)d_in[4];   // [K]
    const float* Wp = (const float*)d_in[5];   // [K,1]
    // d_in[6] = bp: softmax-invariant, unused
    float* out = (float*)d_out;                // [B,K]

    char* ws = (char*)d_ws;
    float*          vQpP = (float*)(ws);                   // 256 KB  [32*8][256]
    unsigned short* WiT  = (unsigned short*)(ws + 262144); // 256 KB  [256][512]
    float*          numP = (float*)(ws + 524288);          // 256 KB  [32*8][256]
    float*          Zp   = (float*)(ws + 786432);          //   1 KB
    float*          mP   = (float*)(ws + 787456);          //   1 KB

    prep_kernel        <<<288, 256, 0, stream>>>(Wi, Wq, vQ, bq, WiT, vQpP);
    scores_fused_kernel<<<dim3(CN / 256, CB), 512, 0, stream>>>(vI, WiT, vQpP, Wp,
                                                                numP, Zp, mP);
    finalize_kernel    <<<CB, 256, 0, stream>>>(numP, Zp, mP, vQpP, out);
}

// Round 8
// 217.181 us; speedup vs baseline: 1.1288x; 1.0389x over previous
//
#include <hip/hip_runtime.h>

// (B,N,D,K) = (32, 2048, 512, 256)
#define CB 32
#define CN 2048
#define CD 512
#define CK 256

typedef __bf16 bf16x8 __attribute__((ext_vector_type(8)));
typedef float  f32x4  __attribute__((ext_vector_type(4)));

__device__ __forceinline__ unsigned pk2bf(float a, float b) {   // RNE pack: 2 f32 -> bf16x2
    union { float f; unsigned u; } x, y; x.f = a; y.f = b;
    unsigned ru = x.u + 0x7fffu + ((x.u >> 16) & 1u);
    unsigned rv = y.u + 0x7fffu + ((y.u >> 16) & 1u);
    return (ru >> 16) | (rv & 0xffff0000u);
}

__device__ __forceinline__ unsigned short bf16r(float a) {      // RNE f32 -> bf16
    union { float f; unsigned u; } x; x.f = a;
    unsigned r = x.u + 0x7fffu + ((x.u >> 16) & 1u);
    return (unsigned short)(r >> 16);
}

__device__ __forceinline__ void glds16(const void* g, void* l) {
    __builtin_amdgcn_global_load_lds(
        (const __attribute__((address_space(1))) void*)g,
        (__attribute__((address_space(3))) void*)l, 16, 0, 0);
}

// ---------------- K0: prep = {WiT transpose tiles: blocks 0..31} ∪
//                          {vQp partial GEMV: blocks 32..287} ----------------
__global__ __launch_bounds__(256) void prep_kernel(
        const float* __restrict__ Wi, const float* __restrict__ Wq,
        const float* __restrict__ vQ, const float* __restrict__ bq,
        unsigned short* __restrict__ WiT, float* __restrict__ vQpP)
{
    const int tid = threadIdx.x;
    if (blockIdx.x < 32) {
        // 64x64 tile transpose Wi[d][k] -> WiT[k][d] (bf16), coalesced both sides
        const int t = blockIdx.x;
        const int d0 = (t >> 2) * 64, k0 = (t & 3) * 64;
        __shared__ float sT[64][68];                 // pad 68: 16B-aligned rows
        const int r = tid >> 4, c4 = (tid & 15) * 4;
        #pragma unroll
        for (int i = 0; i < 4; ++i) {
            float4 v = *reinterpret_cast<const float4*>(
                Wi + (size_t)(d0 + r + i * 16) * CK + k0 + c4);
            *reinterpret_cast<float4*>(&sT[r + i * 16][c4]) = v;
        }
        __syncthreads();
        const int k = tid >> 2, dg = (tid & 3) * 16;
        unsigned short __attribute__((aligned(16))) ov[16];
        #pragma unroll
        for (int j = 0; j < 16; ++j) ov[j] = bf16r(sT[dg + j][k]);
        unsigned short* dst = WiT + (size_t)(k0 + k) * CD + d0 + dg;
        *reinterpret_cast<uint4*>(dst)     = *reinterpret_cast<const uint4*>(&ov[0]);
        *reinterpret_cast<uint4*>(dst + 8) = *reinterpret_cast<const uint4*>(&ov[8]);
    } else {
        // vQpP[b][j][k] = sum_{d in 64-slice j} vQ[b][d]*Wq[d][k]  (+bq at j==0)
        const int bb = blockIdx.x - 32;
        const int b = bb >> 3, j = bb & 7;
        __shared__ float sq[64];
        if (tid < 64) sq[tid] = vQ[b * CD + j * 64 + tid];
        __syncthreads();
        float acc = (j == 0) ? bq[tid] : 0.f;
        const float* wq = Wq + (size_t)j * 64 * CK + tid;
        #pragma unroll
        for (int d = 0; d < 64; d += 8) {
            float wv[8];
            #pragma unroll
            for (int u = 0; u < 8; ++u) wv[u] = wq[(d + u) * CK];   // 8 loads in flight
            #pragma unroll
            for (int u = 0; u < 8; ++u) acc += sq[d + u] * wv[u];
        }
        vQpP[(size_t)bb * CK + tid] = acc;
    }
}

// ---------------- K1: fused scores + online-softmax + K-space num ----------------
// Round-4 structure (BM=128, BK=64, A direct global->reg 1-step-ahead ping-pong,
// B swizzled glds double-buffer, one __syncthreads per step) with the SCRATCH
// SPILL FIXED: A ping-pong buffers are 16 individually NAMED f32x4 registers,
// step loop fully unrolled with compile-time P/Q alternation (no runtime-selected
// array/pointer -> no address-taken scratch allocation; rule #20).
__global__ __launch_bounds__(256, 2) void scores_fused_kernel(
        const float* __restrict__ vI, const unsigned short* __restrict__ WiT,
        const float* __restrict__ vQpP, const float* __restrict__ Wp,
        float* __restrict__ numP, float* __restrict__ Zp, float* __restrict__ mP)
{
    constexpr int BM = 128, BK = 64;
    __shared__ __align__(16) unsigned short sB[2][CK * BK];   // 2 x 32 KB
    float* fb   = (float*)sB[0];      // aliased AFTER the K-loop only
    float* svq  = fb;                 // [256] combined vQp
    float* swp  = fb + 256;           // [256] Wp
    float* sS   = fb + 512;           // [128] row scores
    float* sW   = fb + 640;           // [128] exp weights
    float* snum = fb + 768;           // [4][256] num wave-partials

    const int tid  = threadIdx.x;
    const int b    = blockIdx.y;
    const int n0   = blockIdx.x * BM;
    const int wave = tid >> 6;
    const int lane = tid & 63;
    const int col  = lane & 15;
    const int quad = lane >> 4;

    const float* vIb   = vI + ((size_t)b * CN + n0) * CD;
    // A-row for (mt): 32*wave + mt*16 + col ; d-chunk quad*8 (+s*32)
    const float* aBase = vIb + (size_t)(wave * 32 + col) * CD + quad * 8;

    // B glds source offsets (swizzled chunk): instr i covers rows wave*64+i*8 .. +8
    int gBoff[8];
    #pragma unroll
    for (int i = 0; i < 8; ++i) {
        int row = wave * 64 + i * 8 + (lane >> 3);
        int c   = (lane & 7) ^ (row & 7);
        gBoff[i] = row * CD + c * 8;    // ushort index; +d0 per chunk
    }

    f32x4 acc[2][16];
    #pragma unroll
    for (int mt = 0; mt < 2; ++mt)
        #pragma unroll
        for (int kt = 0; kt < 16; ++kt)
            acc[mt][kt] = (f32x4){0.f, 0.f, 0.f, 0.f};

// ---- named A register sets (NO arrays, NO runtime selection) ----
#define DECL_A(S) f32x4 a##S##0, a##S##1, a##S##2, a##S##3, \
                        a##S##4, a##S##5, a##S##6, a##S##7;
    DECL_A(P)
    DECL_A(Q)

    // idx = mt*4 + s*2 + h : mt0 s0 -> (p0, p0+4), mt0 s1 -> (p0+32, p0+36),
    //                        mt1 s0 -> (p1, p1+4), mt1 s1 -> (p1+32, p1+36)
#define LOADA(S, D0) do {                                                     \
    const float* p0_ = aBase + (D0);                                          \
    const float* p1_ = aBase + 16 * CD + (D0);                                \
    a##S##0 = *reinterpret_cast<const f32x4*>(p0_);                           \
    a##S##1 = *reinterpret_cast<const f32x4*>(p0_ + 4);                       \
    a##S##2 = *reinterpret_cast<const f32x4*>(p0_ + 32);                      \
    a##S##3 = *reinterpret_cast<const f32x4*>(p0_ + 36);                      \
    a##S##4 = *reinterpret_cast<const f32x4*>(p1_);                           \
    a##S##5 = *reinterpret_cast<const f32x4*>(p1_ + 4);                       \
    a##S##6 = *reinterpret_cast<const f32x4*>(p1_ + 32);                      \
    a##S##7 = *reinterpret_cast<const f32x4*>(p1_ + 36);                      \
} while (0)

#define STAGEB(D0, BI) do {                                                   \
    _Pragma("unroll")                                                         \
    for (int i_ = 0; i_ < 8; ++i_)                                            \
        glds16(WiT + gBoff[i_] + (D0),                                        \
               (unsigned short*)sB[BI] + (wave * 8 + i_) * 512);              \
} while (0)

#define PACK2(lo, hi) ({                                                      \
    union { unsigned u[4]; bf16x8 v; } t_;                                    \
    t_.u[0] = pk2bf((lo).x, (lo).y); t_.u[1] = pk2bf((lo).z, (lo).w);         \
    t_.u[2] = pk2bf((hi).x, (hi).y); t_.u[3] = pk2bf((hi).z, (hi).w);         \
    t_.v; })

#define COMPUTE(S, BI) do {                                                   \
    const unsigned short* bufC_ = (const unsigned short*)sB[BI];              \
    bf16x8 f00_ = PACK2(a##S##0, a##S##1);   /* mt0, s0 */                    \
    bf16x8 f01_ = PACK2(a##S##2, a##S##3);   /* mt0, s1 */                    \
    bf16x8 f10_ = PACK2(a##S##4, a##S##5);   /* mt1, s0 */                    \
    bf16x8 f11_ = PACK2(a##S##6, a##S##7);   /* mt1, s1 */                    \
    _Pragma("unroll")                                                         \
    for (int s_ = 0; s_ < 2; ++s_) {                                          \
        const int slot_ = (4 * s_ + quad) ^ (col & 7);                        \
        const bf16x8 am0_ = s_ ? f01_ : f00_;                                 \
        const bf16x8 am1_ = s_ ? f11_ : f10_;                                 \
        _Pragma("unroll")                                                     \
        for (int kc_ = 0; kc_ < 4; ++kc_) {                                   \
            const unsigned short* kb_ = bufC_ + (kc_ * 64 + col) * 64 + slot_ * 8; \
            bf16x8 b0_ = *reinterpret_cast<const bf16x8*>(kb_);               \
            bf16x8 b1_ = *reinterpret_cast<const bf16x8*>(kb_ + 16 * 64);     \
            bf16x8 b2_ = *reinterpret_cast<const bf16x8*>(kb_ + 32 * 64);     \
            bf16x8 b3_ = *reinterpret_cast<const bf16x8*>(kb_ + 48 * 64);     \
            acc[0][kc_ * 4 + 0] = __builtin_amdgcn_mfma_f32_16x16x32_bf16(    \
                am0_, b0_, acc[0][kc_ * 4 + 0], 0, 0, 0);                     \
            acc[1][kc_ * 4 + 0] = __builtin_amdgcn_mfma_f32_16x16x32_bf16(    \
                am1_, b0_, acc[1][kc_ * 4 + 0], 0, 0, 0);                     \
            acc[0][kc_ * 4 + 1] = __builtin_amdgcn_mfma_f32_16x16x32_bf16(    \
                am0_, b1_, acc[0][kc_ * 4 + 1], 0, 0, 0);                     \
            acc[1][kc_ * 4 + 1] = __builtin_amdgcn_mfma_f32_16x16x32_bf16(    \
                am1_, b1_, acc[1][kc_ * 4 + 1], 0, 0, 0);                     \
            acc[0][kc_ * 4 + 2] = __builtin_amdgcn_mfma_f32_16x16x32_bf16(    \
                am0_, b2_, acc[0][kc_ * 4 + 2], 0, 0, 0);                     \
            acc[1][kc_ * 4 + 2] = __builtin_amdgcn_mfma_f32_16x16x32_bf16(    \
                am1_, b2_, acc[1][kc_ * 4 + 2], 0, 0, 0);                     \
            acc[0][kc_ * 4 + 3] = __builtin_amdgcn_mfma_f32_16x16x32_bf16(    \
                am0_, b3_, acc[0][kc_ * 4 + 3], 0, 0, 0);                     \
            acc[1][kc_ * 4 + 3] = __builtin_amdgcn_mfma_f32_16x16x32_bf16(    \
                am1_, b3_, acc[1][kc_ * 4 + 3], 0, 0, 0);                     \
        }                                                                     \
    }                                                                         \
} while (0)

    // B-frag address check (unchanged from r4): row R = (kc*4+u)*16 + col,
    // frag at bufC + R*64 + slot*8 with slot = (4s+quad)^(col&7).

    // prologue: A(0) and B(0) in flight together
    LOADA(P, 0);
    STAGEB(0, 0);
    __syncthreads();

    // steps fully unrolled; step t consumes sB[t&1] + set (t even ? P : Q),
    // prefetches d0=(t+1)*64 into the other buffer/set.
    STAGEB( 64, 1); LOADA(Q,  64); COMPUTE(P, 0); __syncthreads();   // t=0
    STAGEB(128, 0); LOADA(P, 128); COMPUTE(Q, 1); __syncthreads();   // t=1
    STAGEB(192, 1); LOADA(Q, 192); COMPUTE(P, 0); __syncthreads();   // t=2
    STAGEB(256, 0); LOADA(P, 256); COMPUTE(Q, 1); __syncthreads();   // t=3
    STAGEB(320, 1); LOADA(Q, 320); COMPUTE(P, 0); __syncthreads();   // t=4
    STAGEB(384, 0); LOADA(P, 384); COMPUTE(Q, 1); __syncthreads();   // t=5
    STAGEB(448, 1); LOADA(Q, 448); COMPUTE(P, 0); __syncthreads();   // t=6
    COMPUTE(Q, 1); __syncthreads();                                  // t=7

    // ---- epilogue 0: combine vQp partials + Wp into LDS (alias on sB[0]) ----
    {
        float a = 0.f;
        #pragma unroll
        for (int j = 0; j < 8; ++j) a += vQpP[(b * 8 + j) * CK + tid];
        svq[tid] = a;
        swp[tid] = Wp[tid];
    }
    __syncthreads();

    // ---- epilogue 1: per-row scores ----
    float vq[16], wp[16];
    #pragma unroll
    for (int kt = 0; kt < 16; ++kt) {
        vq[kt] = svq[kt * 16 + col];
        wp[kt] = swp[kt * 16 + col];
    }
    float sp[2][4];
    #pragma unroll
    for (int mt = 0; mt < 2; ++mt)
        #pragma unroll
        for (int r = 0; r < 4; ++r) {
            float s = 0.f;
            #pragma unroll
            for (int kt = 0; kt < 16; ++kt) {
                float v = acc[mt][kt][r] + vq[kt];
                v = v > 0.f ? v : 0.01f * v;
                s += v * wp[kt];
            }
            sp[mt][r] = s;
        }
    #pragma unroll
    for (int off = 1; off < 16; off <<= 1)
        #pragma unroll
        for (int mt = 0; mt < 2; ++mt)
            #pragma unroll
            for (int r = 0; r < 4; ++r)
                sp[mt][r] += __shfl_xor(sp[mt][r], off);
    if (col == 0) {
        #pragma unroll
        for (int mt = 0; mt < 2; ++mt)
            #pragma unroll
            for (int r = 0; r < 4; ++r)
                sS[wave * 32 + mt * 16 + quad * 4 + r] = sp[mt][r];
    }
    __syncthreads();

    // ---- epilogue 2: block-local softmax pieces ----
    float m = -1e30f;
    #pragma unroll 8
    for (int i = 0; i < BM; ++i) m = fmaxf(m, sS[i]);
    if (tid < BM) sW[tid] = __expf(sS[tid] - m);
    __syncthreads();
    float z = (tid < BM) ? sW[tid] : 0.f;
    #pragma unroll
    for (int off = 32; off > 0; off >>= 1) z += __shfl_xor(z, off);
    if (lane == 0) sS[wave] = z;     // scores no longer needed
    __syncthreads();
    const int pidx = b * 16 + blockIdx.x;
    if (tid == 0) {
        Zp[pidx] = sS[0] + sS[1] + sS[2] + sS[3];
        mP[pidx] = m;
    }

    // ---- epilogue 3: K-space num from acc registers (vI never re-read) ----
    float w8[2][4];
    #pragma unroll
    for (int mt = 0; mt < 2; ++mt)
        #pragma unroll
        for (int r = 0; r < 4; ++r)
            w8[mt][r] = sW[wave * 32 + mt * 16 + quad * 4 + r];
    float nk[16];
    #pragma unroll
    for (int kt = 0; kt < 16; ++kt) {
        float s = 0.f;
        #pragma unroll
        for (int mt = 0; mt < 2; ++mt)
            #pragma unroll
            for (int r = 0; r < 4; ++r)
                s += w8[mt][r] * acc[mt][kt][r];
        s += __shfl_xor(s, 16);      // reduce across quads (rows)
        s += __shfl_xor(s, 32);
        nk[kt] = s;
    }
    if (quad == 0) {
        #pragma unroll
        for (int kt = 0; kt < 16; ++kt)
            snum[wave * 256 + kt * 16 + col] = nk[kt];
    }
    __syncthreads();
    numP[(size_t)pidx * CK + tid] =
        snum[tid] + snum[256 + tid] + snum[512 + tid] + snum[768 + tid];
}

// ---------------- K2: combine partials -> out = num/Z + vQp (elementwise) ----------------
__global__ __launch_bounds__(256) void finalize_kernel(
        const float* __restrict__ numP, const float* __restrict__ Zp,
        const float* __restrict__ mP, const float* __restrict__ vQpP,
        float* __restrict__ out)
{
    const int b = blockIdx.x, tid = threadIdx.x;
    float M = -1e30f;
    #pragma unroll
    for (int j = 0; j < 16; ++j) M = fmaxf(M, mP[b * 16 + j]);
    float w[16]; float Zt = 0.f;
    #pragma unroll
    for (int j = 0; j < 16; ++j) {
        w[j] = __expf(mP[b * 16 + j] - M);
        Zt += w[j] * Zp[b * 16 + j];
    }
    const float inv = 1.f / Zt;
    float s = 0.f;
    #pragma unroll
    for (int j = 0; j < 16; ++j) s += w[j] * numP[(size_t)(b * 16 + j) * CK + tid];
    float vq = 0.f;
    #pragma unroll
    for (int j = 0; j < 8; ++j) vq += vQpP[(size_t)(b * 8 + j) * CK + tid];
    out[b * CK + tid] = s * inv + vq;
}

extern "C" void kernel_launch(void* const* d_in, const int* in_sizes, int n_in,
                              void* d_out, int out_size, void* d_ws, size_t ws_size,
                              hipStream_t stream)
{
    const float* vI = (const float*)d_in[0];   // [B,N,D]
    const float* vQ = (const float*)d_in[1];   // [B,D]
    const float* Wi = (const float*)d_in[2];   // [D,K]
    const float* Wq = (const float*)d_in[3];   // [D,K]
    const float* bq = (const float*)d_in[4];   // [K]
    const float* Wp = (const float*)d_in[5];   // [K,1]
    // d_in[6] = bp: softmax-invariant, unused
    float* out = (float*)d_out;                // [B,K]

    char* ws = (char*)d_ws;
    float*          vQpP = (float*)(ws);                   // 256 KB  [32*8][256]
    unsigned short* WiT  = (unsigned short*)(ws + 262144); // 256 KB  [256][512]
    float*          numP = (float*)(ws + 524288);          // 512 KB  [32*16][256]
    float*          Zp   = (float*)(ws + 524288 + 524288); //   2 KB
    float*          mP   = (float*)(ws + 1048576 + 2048);  //   2 KB

    prep_kernel        <<<288, 256, 0, stream>>>(Wi, Wq, vQ, bq, WiT, vQpP);
    scores_fused_kernel<<<dim3(CN / 128, CB), 256, 0, stream>>>(vI, WiT, vQpP, Wp,
                                                                numP, Zp, mP);
    finalize_kernel    <<<CB, 256, 0, stream>>>(numP, Zp, mP, vQpP, out);
}

// Round 9
// 215.355 us; speedup vs baseline: 1.1384x; 1.0085x over previous
//
#include <hip/hip_runtime.h>

// (B,N,D,K) = (32, 2048, 512, 256)
#define CB 32
#define CN 2048
#define CD 512
#define CK 256

typedef __bf16 bf16x8 __attribute__((ext_vector_type(8)));
typedef float  f32x4  __attribute__((ext_vector_type(4)));

__device__ __forceinline__ unsigned pk2bf(float a, float b) {   // RNE pack: 2 f32 -> bf16x2
    union { float f; unsigned u; } x, y; x.f = a; y.f = b;
    unsigned ru = x.u + 0x7fffu + ((x.u >> 16) & 1u);
    unsigned rv = y.u + 0x7fffu + ((y.u >> 16) & 1u);
    return (ru >> 16) | (rv & 0xffff0000u);
}

__device__ __forceinline__ unsigned short bf16r(float a) {      // RNE f32 -> bf16
    union { float f; unsigned u; } x; x.f = a;
    unsigned r = x.u + 0x7fffu + ((x.u >> 16) & 1u);
    return (unsigned short)(r >> 16);
}

__device__ __forceinline__ void glds16(const void* g, void* l) {
    __builtin_amdgcn_global_load_lds(
        (const __attribute__((address_space(1))) void*)g,
        (__attribute__((address_space(3))) void*)l, 16, 0, 0);
}

// ---------------- K0: prep = {WiT transpose tiles: blocks 0..31} ∪
//                          {vQp partial GEMV: blocks 32..287} ----------------
__global__ __launch_bounds__(256) void prep_kernel(
        const float* __restrict__ Wi, const float* __restrict__ Wq,
        const float* __restrict__ vQ, const float* __restrict__ bq,
        unsigned short* __restrict__ WiT, float* __restrict__ vQpP)
{
    const int tid = threadIdx.x;
    if (blockIdx.x < 32) {
        // 64x64 tile transpose Wi[d][k] -> WiT[k][d] (bf16), coalesced both sides
        const int t = blockIdx.x;
        const int d0 = (t >> 2) * 64, k0 = (t & 3) * 64;
        __shared__ float sT[64][68];                 // pad 68: 16B-aligned rows
        const int r = tid >> 4, c4 = (tid & 15) * 4;
        #pragma unroll
        for (int i = 0; i < 4; ++i) {
            float4 v = *reinterpret_cast<const float4*>(
                Wi + (size_t)(d0 + r + i * 16) * CK + k0 + c4);
            *reinterpret_cast<float4*>(&sT[r + i * 16][c4]) = v;
        }
        __syncthreads();
        const int k = tid >> 2, dg = (tid & 3) * 16;
        unsigned short __attribute__((aligned(16))) ov[16];
        #pragma unroll
        for (int j = 0; j < 16; ++j) ov[j] = bf16r(sT[dg + j][k]);
        unsigned short* dst = WiT + (size_t)(k0 + k) * CD + d0 + dg;
        *reinterpret_cast<uint4*>(dst)     = *reinterpret_cast<const uint4*>(&ov[0]);
        *reinterpret_cast<uint4*>(dst + 8) = *reinterpret_cast<const uint4*>(&ov[8]);
    } else {
        // vQpP[b][j][k] = sum_{d in 64-slice j} vQ[b][d]*Wq[d][k]  (+bq at j==0)
        const int bb = blockIdx.x - 32;
        const int b = bb >> 3, j = bb & 7;
        __shared__ float sq[64];
        if (tid < 64) sq[tid] = vQ[b * CD + j * 64 + tid];
        __syncthreads();
        float acc = (j == 0) ? bq[tid] : 0.f;
        const float* wq = Wq + (size_t)j * 64 * CK + tid;
        #pragma unroll
        for (int d = 0; d < 64; d += 8) {
            float wv[8];
            #pragma unroll
            for (int u = 0; u < 8; ++u) wv[u] = wq[(d + u) * CK];   // 8 loads in flight
            #pragma unroll
            for (int u = 0; u < 8; ++u) acc += sq[d + u] * wv[u];
        }
        vQpP[(size_t)bb * CK + tid] = acc;
    }
}

// ---------------- K1: fused scores + online-softmax + K-space num ----------------
// r8 skeleton (named A regs, no scratch) + T4 counted-vmcnt barriers:
// per mid step: STAGEB (oldest 8 in vmcnt FIFO) | LOADA (newest 8) | COMPUTE |
// s_waitcnt vmcnt(8) ; s_barrier  -- drains glds only; A-loads stay in flight
// across the barrier and are waited at first use next step.
__global__ __launch_bounds__(256, 2) void scores_fused_kernel(
        const float* __restrict__ vI, const unsigned short* __restrict__ WiT,
        const float* __restrict__ vQpP, const float* __restrict__ Wp,
        float* __restrict__ numP, float* __restrict__ Zp, float* __restrict__ mP)
{
    constexpr int BM = 128, BK = 64;
    __shared__ __align__(16) unsigned short sB[2][CK * BK];   // 2 x 32 KB
    float* fb   = (float*)sB[0];      // aliased AFTER the K-loop only
    float* svq  = fb;                 // [256] combined vQp
    float* swp  = fb + 256;           // [256] Wp
    float* sS   = fb + 512;           // [128] row scores
    float* sW   = fb + 640;           // [128] exp weights
    float* snum = fb + 768;           // [4][256] num wave-partials

    const int tid  = threadIdx.x;
    const int b    = blockIdx.y;
    const int n0   = blockIdx.x * BM;
    const int wave = tid >> 6;
    const int lane = tid & 63;
    const int col  = lane & 15;
    const int quad = lane >> 4;

    const float* vIb   = vI + ((size_t)b * CN + n0) * CD;
    // A-row for (mt): 32*wave + mt*16 + col ; d-chunk quad*8 (+s*32)
    const float* aBase = vIb + (size_t)(wave * 32 + col) * CD + quad * 8;

    // B glds source offsets (swizzled chunk): instr i covers rows wave*64+i*8 .. +8
    int gBoff[8];
    #pragma unroll
    for (int i = 0; i < 8; ++i) {
        int row = wave * 64 + i * 8 + (lane >> 3);
        int c   = (lane & 7) ^ (row & 7);
        gBoff[i] = row * CD + c * 8;    // ushort index; +d0 per chunk
    }

    f32x4 acc[2][16];
    #pragma unroll
    for (int mt = 0; mt < 2; ++mt)
        #pragma unroll
        for (int kt = 0; kt < 16; ++kt)
            acc[mt][kt] = (f32x4){0.f, 0.f, 0.f, 0.f};

// ---- named A register sets (NO arrays, NO runtime selection) ----
#define DECL_A(S) f32x4 a##S##0, a##S##1, a##S##2, a##S##3, \
                        a##S##4, a##S##5, a##S##6, a##S##7;
    DECL_A(P)
    DECL_A(Q)

#define LOADA(S, D0) do {                                                     \
    const float* p0_ = aBase + (D0);                                          \
    const float* p1_ = aBase + 16 * CD + (D0);                                \
    a##S##0 = *reinterpret_cast<const f32x4*>(p0_);                           \
    a##S##1 = *reinterpret_cast<const f32x4*>(p0_ + 4);                       \
    a##S##2 = *reinterpret_cast<const f32x4*>(p0_ + 32);                      \
    a##S##3 = *reinterpret_cast<const f32x4*>(p0_ + 36);                      \
    a##S##4 = *reinterpret_cast<const f32x4*>(p1_);                           \
    a##S##5 = *reinterpret_cast<const f32x4*>(p1_ + 4);                       \
    a##S##6 = *reinterpret_cast<const f32x4*>(p1_ + 32);                      \
    a##S##7 = *reinterpret_cast<const f32x4*>(p1_ + 36);                      \
} while (0)

#define STAGEB(D0, BI) do {                                                   \
    _Pragma("unroll")                                                         \
    for (int i_ = 0; i_ < 8; ++i_)                                            \
        glds16(WiT + gBoff[i_] + (D0),                                        \
               (unsigned short*)sB[BI] + (wave * 8 + i_) * 512);              \
} while (0)

#define PACK2(lo, hi) ({                                                      \
    union { unsigned u[4]; bf16x8 v; } t_;                                    \
    t_.u[0] = pk2bf((lo).x, (lo).y); t_.u[1] = pk2bf((lo).z, (lo).w);         \
    t_.u[2] = pk2bf((hi).x, (hi).y); t_.u[3] = pk2bf((hi).z, (hi).w);         \
    t_.v; })

#define COMPUTE(S, BI) do {                                                   \
    const unsigned short* bufC_ = (const unsigned short*)sB[BI];              \
    bf16x8 f00_ = PACK2(a##S##0, a##S##1);   /* mt0, s0 */                    \
    bf16x8 f01_ = PACK2(a##S##2, a##S##3);   /* mt0, s1 */                    \
    bf16x8 f10_ = PACK2(a##S##4, a##S##5);   /* mt1, s0 */                    \
    bf16x8 f11_ = PACK2(a##S##6, a##S##7);   /* mt1, s1 */                    \
    _Pragma("unroll")                                                         \
    for (int s_ = 0; s_ < 2; ++s_) {                                          \
        const int slot_ = (4 * s_ + quad) ^ (col & 7);                        \
        const bf16x8 am0_ = s_ ? f01_ : f00_;                                 \
        const bf16x8 am1_ = s_ ? f11_ : f10_;                                 \
        _Pragma("unroll")                                                     \
        for (int kc_ = 0; kc_ < 4; ++kc_) {                                   \
            const unsigned short* kb_ = bufC_ + (kc_ * 64 + col) * 64 + slot_ * 8; \
            bf16x8 b0_ = *reinterpret_cast<const bf16x8*>(kb_);               \
            bf16x8 b1_ = *reinterpret_cast<const bf16x8*>(kb_ + 16 * 64);     \
            bf16x8 b2_ = *reinterpret_cast<const bf16x8*>(kb_ + 32 * 64);     \
            bf16x8 b3_ = *reinterpret_cast<const bf16x8*>(kb_ + 48 * 64);     \
            acc[0][kc_ * 4 + 0] = __builtin_amdgcn_mfma_f32_16x16x32_bf16(    \
                am0_, b0_, acc[0][kc_ * 4 + 0], 0, 0, 0);                     \
            acc[1][kc_ * 4 + 0] = __builtin_amdgcn_mfma_f32_16x16x32_bf16(    \
                am1_, b0_, acc[1][kc_ * 4 + 0], 0, 0, 0);                     \
            acc[0][kc_ * 4 + 1] = __builtin_amdgcn_mfma_f32_16x16x32_bf16(    \
                am0_, b1_, acc[0][kc_ * 4 + 1], 0, 0, 0);                     \
            acc[1][kc_ * 4 + 1] = __builtin_amdgcn_mfma_f32_16x16x32_bf16(    \
                am1_, b1_, acc[1][kc_ * 4 + 1], 0, 0, 0);                     \
            acc[0][kc_ * 4 + 2] = __builtin_amdgcn_mfma_f32_16x16x32_bf16(    \
                am0_, b2_, acc[0][kc_ * 4 + 2], 0, 0, 0);                     \
            acc[1][kc_ * 4 + 2] = __builtin_amdgcn_mfma_f32_16x16x32_bf16(    \
                am1_, b2_, acc[1][kc_ * 4 + 2], 0, 0, 0);                     \
            acc[0][kc_ * 4 + 3] = __builtin_amdgcn_mfma_f32_16x16x32_bf16(    \
                am0_, b3_, acc[0][kc_ * 4 + 3], 0, 0, 0);                     \
            acc[1][kc_ * 4 + 3] = __builtin_amdgcn_mfma_f32_16x16x32_bf16(    \
                am1_, b3_, acc[1][kc_ * 4 + 3], 0, 0, 0);                     \
        }                                                                     \
    }                                                                         \
} while (0)

// counted-vmcnt step barrier: drain only the 8 glds (oldest); A stays in flight
#define STEP_BARRIER() do {                                                   \
    asm volatile("s_waitcnt vmcnt(8)" ::: "memory");                          \
    __builtin_amdgcn_sched_barrier(0);                                        \
    __builtin_amdgcn_s_barrier();                                             \
} while (0)

    // prologue: A(0) and B(0) in flight together; full drain once
    LOADA(P, 0);
    STAGEB(0, 0);
    __syncthreads();

    // steps fully unrolled; step t consumes sB[t&1] + set (t even ? P : Q),
    // prefetches d0=(t+1)*64 into the other buffer/set.
    STAGEB( 64, 1); __builtin_amdgcn_sched_barrier(0);
    LOADA(Q,  64);  __builtin_amdgcn_sched_barrier(0);
    COMPUTE(P, 0);  STEP_BARRIER();                                  // t=0
    STAGEB(128, 0); __builtin_amdgcn_sched_barrier(0);
    LOADA(P, 128);  __builtin_amdgcn_sched_barrier(0);
    COMPUTE(Q, 1);  STEP_BARRIER();                                  // t=1
    STAGEB(192, 1); __builtin_amdgcn_sched_barrier(0);
    LOADA(Q, 192);  __builtin_amdgcn_sched_barrier(0);
    COMPUTE(P, 0);  STEP_BARRIER();                                  // t=2
    STAGEB(256, 0); __builtin_amdgcn_sched_barrier(0);
    LOADA(P, 256);  __builtin_amdgcn_sched_barrier(0);
    COMPUTE(Q, 1);  STEP_BARRIER();                                  // t=3
    STAGEB(320, 1); __builtin_amdgcn_sched_barrier(0);
    LOADA(Q, 320);  __builtin_amdgcn_sched_barrier(0);
    COMPUTE(P, 0);  STEP_BARRIER();                                  // t=4
    STAGEB(384, 0); __builtin_amdgcn_sched_barrier(0);
    LOADA(P, 384);  __builtin_amdgcn_sched_barrier(0);
    COMPUTE(Q, 1);  STEP_BARRIER();                                  // t=5
    STAGEB(448, 1); __builtin_amdgcn_sched_barrier(0);
    LOADA(Q, 448);  __builtin_amdgcn_sched_barrier(0);
    COMPUTE(P, 0);  STEP_BARRIER();                                  // t=6
    COMPUTE(Q, 1);                                                   // t=7
    __syncthreads();   // full drain before LDS aliasing

    // ---- epilogue 0: combine vQp partials + Wp into LDS (alias on sB[0]) ----
    {
        float a = 0.f;
        #pragma unroll
        for (int j = 0; j < 8; ++j) a += vQpP[(b * 8 + j) * CK + tid];
        svq[tid] = a;
        swp[tid] = Wp[tid];
    }
    __syncthreads();

    // ---- epilogue 1: per-row scores ----
    float vq[16], wp[16];
    #pragma unroll
    for (int kt = 0; kt < 16; ++kt) {
        vq[kt] = svq[kt * 16 + col];
        wp[kt] = swp[kt * 16 + col];
    }
    float sp[2][4];
    #pragma unroll
    for (int mt = 0; mt < 2; ++mt)
        #pragma unroll
        for (int r = 0; r < 4; ++r) {
            float s = 0.f;
            #pragma unroll
            for (int kt = 0; kt < 16; ++kt) {
                float v = acc[mt][kt][r] + vq[kt];
                v = v > 0.f ? v : 0.01f * v;
                s += v * wp[kt];
            }
            sp[mt][r] = s;
        }
    #pragma unroll
    for (int off = 1; off < 16; off <<= 1)
        #pragma unroll
        for (int mt = 0; mt < 2; ++mt)
            #pragma unroll
            for (int r = 0; r < 4; ++r)
                sp[mt][r] += __shfl_xor(sp[mt][r], off);
    if (col == 0) {
        #pragma unroll
        for (int mt = 0; mt < 2; ++mt)
            #pragma unroll
            for (int r = 0; r < 4; ++r)
                sS[wave * 32 + mt * 16 + quad * 4 + r] = sp[mt][r];
    }
    __syncthreads();

    // ---- epilogue 2: block-local softmax pieces ----
    float m = -1e30f;
    #pragma unroll 8
    for (int i = 0; i < BM; ++i) m = fmaxf(m, sS[i]);
    if (tid < BM) sW[tid] = __expf(sS[tid] - m);
    __syncthreads();
    float z = (tid < BM) ? sW[tid] : 0.f;
    #pragma unroll
    for (int off = 32; off > 0; off >>= 1) z += __shfl_xor(z, off);
    if (lane == 0) sS[wave] = z;     // scores no longer needed
    __syncthreads();
    const int pidx = b * 16 + blockIdx.x;
    if (tid == 0) {
        Zp[pidx] = sS[0] + sS[1] + sS[2] + sS[3];
        mP[pidx] = m;
    }

    // ---- epilogue 3: K-space num from acc registers (vI never re-read) ----
    float w8[2][4];
    #pragma unroll
    for (int mt = 0; mt < 2; ++mt)
        #pragma unroll
        for (int r = 0; r < 4; ++r)
            w8[mt][r] = sW[wave * 32 + mt * 16 + quad * 4 + r];
    float nk[16];
    #pragma unroll
    for (int kt = 0; kt < 16; ++kt) {
        float s = 0.f;
        #pragma unroll
        for (int mt = 0; mt < 2; ++mt)
            #pragma unroll
            for (int r = 0; r < 4; ++r)
                s += w8[mt][r] * acc[mt][kt][r];
        s += __shfl_xor(s, 16);      // reduce across quads (rows)
        s += __shfl_xor(s, 32);
        nk[kt] = s;
    }
    if (quad == 0) {
        #pragma unroll
        for (int kt = 0; kt < 16; ++kt)
            snum[wave * 256 + kt * 16 + col] = nk[kt];
    }
    __syncthreads();
    numP[(size_t)pidx * CK + tid] =
        snum[tid] + snum[256 + tid] + snum[512 + tid] + snum[768 + tid];
}

// ---------------- K2: combine partials -> out = num/Z + vQp (elementwise) ----------------
__global__ __launch_bounds__(256) void finalize_kernel(
        const float* __restrict__ numP, const float* __restrict__ Zp,
        const float* __restrict__ mP, const float* __restrict__ vQpP,
        float* __restrict__ out)
{
    const int b = blockIdx.x, tid = threadIdx.x;
    float M = -1e30f;
    #pragma unroll
    for (int j = 0; j < 16; ++j) M = fmaxf(M, mP[b * 16 + j]);
    float w[16]; float Zt = 0.f;
    #pragma unroll
    for (int j = 0; j < 16; ++j) {
        w[j] = __expf(mP[b * 16 + j] - M);
        Zt += w[j] * Zp[b * 16 + j];
    }
    const float inv = 1.f / Zt;
    float s = 0.f;
    #pragma unroll
    for (int j = 0; j < 16; ++j) s += w[j] * numP[(size_t)(b * 16 + j) * CK + tid];
    float vq = 0.f;
    #pragma unroll
    for (int j = 0; j < 8; ++j) vq += vQpP[(size_t)(b * 8 + j) * CK + tid];
    out[b * CK + tid] = s * inv + vq;
}

extern "C" void kernel_launch(void* const* d_in, const int* in_sizes, int n_in,
                              void* d_out, int out_size, void* d_ws, size_t ws_size,
                              hipStream_t stream)
{
    const float* vI = (const float*)d_in[0];   // [B,N,D]
    const float* vQ = (const float*)d_in[1];   // [B,D]
    const float* Wi = (const float*)d_in[2];   // [D,K]
    const float* Wq = (const float*)d_in[3];   // [D,K]
    const float* bq = (const float*)d_in[4];   // [K]
    const float* Wp = (const float*)d_in[5];   // [K,1]
    // d_in[6] = bp: softmax-invariant, unused
    float* out = (float*)d_out;                // [B,K]

    char* ws = (char*)d_ws;
    float*          vQpP = (float*)(ws);                   // 256 KB  [32*8][256]
    unsigned short* WiT  = (unsigned short*)(ws + 262144); // 256 KB  [256][512]
    float*          numP = (float*)(ws + 524288);          // 512 KB  [32*16][256]
    float*          Zp   = (float*)(ws + 524288 + 524288); //   2 KB
    float*          mP   = (float*)(ws + 1048576 + 2048);  //   2 KB

    prep_kernel        <<<288, 256, 0, stream>>>(Wi, Wq, vQ, bq, WiT, vQpP);
    scores_fused_kernel<<<dim3(CN / 128, CB), 256, 0, stream>>>(vI, WiT, vQpP, Wp,
                                                                numP, Zp, mP);
    finalize_kernel    <<<CB, 256, 0, stream>>>(numP, Zp, mP, vQpP, out);
}